// Round 5
// baseline (115.574 us; speedup 1.0000x reference)
//
#include <hip/hip_runtime.h>
#include <hip/hip_bf16.h>

typedef __attribute__((ext_vector_type(8))) short short8;
typedef __attribute__((ext_vector_type(4))) float f32x4;
typedef unsigned short u16;
typedef unsigned int u32;

constexpr int CB = 4, CN = 2048, CF = 128, CD = 64, CH = 4;
constexpr int IT = 16;   // i-rows per attn block

__device__ inline u32 fmap(float f) {
    u32 b = __float_as_uint(f);
    return b ^ ((u32)(((int)b) >> 31) | 0x80000000u);
}
__device__ inline float funmap(u32 u) {
    u32 b = (u & 0x80000000u) ? (u ^ 0x80000000u) : ~u;
    return __uint_as_float(b);
}
__device__ inline u16 bf16bits(float v) {
    __hip_bfloat16 b = __float2bfloat16(v);
    return *reinterpret_cast<u16*>(&b);
}

// ---------------------------------------------------------------------------
// Kernel 0: fused prep. Blocks [0,16384): pack adjacency -> bitmask (+ init
// smax). Blocks [16384,16512): W [H][F][D] f32 -> WT hi/lo bf16 [H][D][F].
// ---------------------------------------------------------------------------
__global__ __launch_bounds__(256) void prep_k(const int* __restrict__ A,
                                              const float* __restrict__ W,
                                              u32* __restrict__ mask,
                                              u32* __restrict__ smax_u,
                                              u16* __restrict__ WThi,
                                              u16* __restrict__ WTlo) {
    int blk = blockIdx.x, t = threadIdx.x;
    if (blk < 16384) {
        int gid = blk * 256 + t;
        if (blk == 0 && t < CH * CB) smax_u[t] = 0u;  // ~ -inf under fmap
        unsigned long long mk = __ballot(A[gid] > 0);
        if ((t & 63) == 0) {
            mask[gid >> 5] = (u32)mk;
            mask[(gid >> 5) + 1] = (u32)(mk >> 32);
        }
    } else {
        int idx = (blk - 16384) * 256 + t;   // H*F*D = 32768
        int h = idx >> 13;
        int f = (idx >> 6) & 127;
        int d = idx & 63;
        float v = W[idx];
        __hip_bfloat16 bh = __float2bfloat16(v);
        float lo = v - __bfloat162float(bh);
        int o = (h * CD + d) * CF + f;
        WThi[o] = *reinterpret_cast<u16*>(&bh);
        WTlo[o] = bf16bits(lo);
    }
}

// ---------------------------------------------------------------------------
// Kernel 1: MFMA projection. wave = (head, 16-row tile); block = 4 waves.
// Split-bf16: Xhi*Whi + Xhi*Wlo + Xlo*Whi.
// Emits hT bf16 [h][b][d][j], s f32, E=exp(s) f32, smax atomicMax.
// ---------------------------------------------------------------------------
__global__ __launch_bounds__(256) void proj_k(const float* __restrict__ X,
                                              const u16* __restrict__ WThi,
                                              const u16* __restrict__ WTlo,
                                              const float* __restrict__ AK,
                                              u16* __restrict__ hT,
                                              float* __restrict__ sout,
                                              float* __restrict__ eout,
                                              u32* __restrict__ smax_u) {
    __shared__ float tr[4][CD][17];   // per-wave transpose staging

    int blk = blockIdx.x;             // b*128 + ntile
    int ntile = blk & 127;
    int b = blk >> 7;
    int n0 = ntile * 16;
    int t = threadIdx.x;
    int w = t >> 6, l = t & 63;
    int h = w;
    int row_l = l & 15, jg = l >> 4;

    const float* xrow = X + ((size_t)b * CN + n0 + row_l) * CF + jg * 8;
    const u16* whi = WThi + (size_t)h * CD * CF;
    const u16* wlo = WTlo + (size_t)h * CD * CF;

    f32x4 c[4];
    f32x4 zero = {0.f, 0.f, 0.f, 0.f};
#pragma unroll
    for (int dt = 0; dt < 4; ++dt) c[dt] = zero;

#pragma unroll
    for (int kk = 0; kk < 4; ++kk) {
        float4 xa = *reinterpret_cast<const float4*>(xrow + kk * 32);
        float4 xb = *reinterpret_cast<const float4*>(xrow + kk * 32 + 4);
        float xv[8] = {xa.x, xa.y, xa.z, xa.w, xb.x, xb.y, xb.z, xb.w};
        short8 ahi, alo;
#pragma unroll
        for (int e = 0; e < 8; ++e) {
            __hip_bfloat16 bh = __float2bfloat16(xv[e]);
            ahi[e] = (short)*reinterpret_cast<u16*>(&bh);
            alo[e] = (short)bf16bits(xv[e] - __bfloat162float(bh));
        }
#pragma unroll
        for (int dt = 0; dt < 4; ++dt) {
            const u16* wp = whi + (dt * 16 + row_l) * CF + kk * 32 + jg * 8;
            const u16* wq = wlo + (dt * 16 + row_l) * CF + kk * 32 + jg * 8;
            short8 bhi = *reinterpret_cast<const short8*>(wp);
            short8 blo = *reinterpret_cast<const short8*>(wq);
            c[dt] = __builtin_amdgcn_mfma_f32_16x16x32_bf16(ahi, bhi, c[dt], 0, 0, 0);
            c[dt] = __builtin_amdgcn_mfma_f32_16x16x32_bf16(ahi, blo, c[dt], 0, 0, 0);
            c[dt] = __builtin_amdgcn_mfma_f32_16x16x32_bf16(alo, bhi, c[dt], 0, 0, 0);
        }
    }

    // ---- s = h . a ----
    float av[4];
#pragma unroll
    for (int dt = 0; dt < 4; ++dt) av[dt] = AK[h * CD + dt * 16 + row_l];
    float sacc[4];
#pragma unroll
    for (int r = 0; r < 4; ++r)
        sacc[r] = c[0][r] * av[0] + c[1][r] * av[1] + c[2][r] * av[2] + c[3][r] * av[3];
#pragma unroll
    for (int off = 1; off <= 8; off <<= 1)
#pragma unroll
        for (int r = 0; r < 4; ++r) sacc[r] += __shfl_xor(sacc[r], off, 64);

    float mx = fmaxf(fmaxf(sacc[0], sacc[1]), fmaxf(sacc[2], sacc[3]));
    mx = fmaxf(mx, __shfl_xor(mx, 16, 64));
    mx = fmaxf(mx, __shfl_xor(mx, 32, 64));
    if (l == 0) atomicMax(&smax_u[h * CB + b], fmap(mx));

    if (row_l == 0) {
#pragma unroll
        for (int r = 0; r < 4; ++r) {
            size_t si = (size_t)(h * CB + b) * CN + n0 + jg * 4 + r;
            sout[si] = sacc[r];
            eout[si] = __expf(sacc[r]);
        }
    }

    // ---- transpose h to d-major bf16 hT via LDS ----
#pragma unroll
    for (int dt = 0; dt < 4; ++dt)
#pragma unroll
        for (int r = 0; r < 4; ++r) tr[w][dt * 16 + row_l][jg * 4 + r] = c[dt][r];
    __syncthreads();

#pragma unroll
    for (int ch = 0; ch < 2; ++ch) {
        short8 pk;
#pragma unroll
        for (int e = 0; e < 8; ++e) pk[e] = (short)bf16bits(tr[w][l][ch * 8 + e]);
        *reinterpret_cast<short8*>(hT + ((size_t)((h * CB + b) * CD + l)) * CN + n0 + ch * 8) = pk;
    }
}

// ---------------------------------------------------------------------------
// Kernel 2: fused flash PV + head-mean + leaky. block = (b, 16-row i-tile),
// 512 threads = 8 waves = (head, j-half of 1024). Grid = 4*128 = 512.
// Weight w = mask ? max(Ei*Ej, Ci) : 0 ; denominator from ones-MFMA of the
// SAME bf16-rounded A-frag. Partials cross-wave via LDS; final out written
// directly (no partC / combine kernel).
// ---------------------------------------------------------------------------
__global__ __launch_bounds__(512) void attn_k(const u16* __restrict__ hT,
                                              const float* __restrict__ s_ws,
                                              const float* __restrict__ e_ws,
                                              const u32* __restrict__ smax_u,
                                              const u32* __restrict__ mask32,
                                              float* __restrict__ out) {
    __shared__ u32 m_lds[IT][65];          // 4.2 KB mask words (pad)
    __shared__ float cbuf[CH][2][IT][65];  // 33.3 KB partial C (pad 65)
    __shared__ float lbuf[CH][2][IT];      // 0.5 KB denominators

    int blk = blockIdx.x;
    int b = blk >> 7;
    int i0 = (blk & 127) * IT;
    int t = threadIdx.x, w = t >> 6, l = t & 63;
    int hq = w >> 1, jh = w & 1;
    int row_l = l & 15, jg = l >> 4;
    int j_base = jh * 1024;

    for (int idx = t; idx < IT * 64; idx += 512) {
        int r = idx >> 6, wd = idx & 63;
        m_lds[r][wd] = mask32[(size_t)(i0 + r) * 64 + wd];
    }
    __syncthreads();

    float smax = funmap(smax_u[hq * CB + b]);
    float si = s_ws[(size_t)(hq * CB + b) * CN + i0 + row_l];
    float m = fmaxf(si + smax, 0.f);
    float Ei = __expf(si - m), Ci = __expf(-m);

    f32x4 c[4], cl;
    f32x4 zero = {0.f, 0.f, 0.f, 0.f};
#pragma unroll
    for (int dt = 0; dt < 4; ++dt) c[dt] = zero;
    cl = zero;

    short8 ones;
#pragma unroll
    for (int e = 0; e < 8; ++e) ones[e] = (short)0x3F80;  // bf16 1.0

    const u16* bp[4];
#pragma unroll
    for (int dt = 0; dt < 4; ++dt)
        bp[dt] = hT + ((size_t)((hq * CB + b) * CD + dt * 16 + row_l)) * CN + j_base + jg * 8;
    const float* ep = e_ws + (size_t)(hq * CB + b) * CN + j_base + jg * 8;

#pragma unroll 2
    for (int kk = 0; kk < 32; ++kk) {
        int j0 = kk * 32;
        short8 bf[4];
#pragma unroll
        for (int dt = 0; dt < 4; ++dt)
            bf[dt] = *reinterpret_cast<const short8*>(bp[dt] + j0);

        f32x4 ej0 = *reinterpret_cast<const f32x4*>(ep + j0);
        f32x4 ej1 = *reinterpret_cast<const f32x4*>(ep + j0 + 4);
        u32 byte = m_lds[row_l][jh * 32 + kk] >> (jg * 8);

        short8 af;
#pragma unroll
        for (int e = 0; e < 8; ++e) {
            float ejv = (e < 4) ? ej0[e] : ej1[e - 4];
            float tv = fmaxf(Ei * ejv, Ci);
            float wv = ((byte >> e) & 1u) ? tv : 0.f;
            af[e] = (short)bf16bits(wv);
        }

#pragma unroll
        for (int dt = 0; dt < 4; ++dt)
            c[dt] = __builtin_amdgcn_mfma_f32_16x16x32_bf16(af, bf[dt], c[dt], 0, 0, 0);
        cl = __builtin_amdgcn_mfma_f32_16x16x32_bf16(af, ones, cl, 0, 0, 0);
    }

    // stage partials. C/D layout: col = lane&15, row = (lane>>4)*4 + reg
#pragma unroll
    for (int dt = 0; dt < 4; ++dt)
#pragma unroll
        for (int r = 0; r < 4; ++r)
            cbuf[hq][jh][jg * 4 + r][dt * 16 + row_l] = c[dt][r];
    if (row_l == 0)
#pragma unroll
        for (int r = 0; r < 4; ++r) lbuf[hq][jh][jg * 4 + r] = cl[r];
    __syncthreads();

    // epilogue: half-sum, divide, head-mean, leaky, final store
    for (int idx = t; idx < IT * CD; idx += 512) {
        int row = idx >> 6, d = idx & 63;
        float acc = 0.f;
#pragma unroll
        for (int h = 0; h < CH; ++h) {
            float num = cbuf[h][0][row][d] + cbuf[h][1][row][d];
            float den = lbuf[h][0][row] + lbuf[h][1][row];
            acc += num / fmaxf(den, 1e-30f);
        }
        float o = acc * 0.25f;
        out[((size_t)b * CN + i0 + row) * CD + d] = o > 0.f ? o : 0.2f * o;
    }
}

// ---------------------------------------------------------------------------
extern "C" void kernel_launch(void* const* d_in, const int* in_sizes, int n_in,
                              void* d_out, int out_size, void* d_ws, size_t ws_size,
                              hipStream_t stream) {
    const float* X  = (const float*)d_in[0];   // [B,N,F]
    const int*   A  = (const int*)d_in[1];     // [N,N]
    const float* W  = (const float*)d_in[2];   // [H,F,D]
    const float* AK = (const float*)d_in[3];   // [H,D]
    float* out = (float*)d_out;                // [B,N,D]

    char* w = (char*)d_ws;
    float* s_ws = (float*)w;    w += 131072;     // 16*2048 f32
    float* e_ws = (float*)w;    w += 131072;     // 16*2048 f32
    u32* smax_ws = (u32*)w;     w += 256;
    u32* mask_ws = (u32*)w;     w += 524288;     // 2048*64 u32
    u16* hT = (u16*)w;          w += 4194304;    // 16*64*2048 bf16
    u16* WThi = (u16*)w;        w += 65536;      // 4*64*128 bf16
    u16* WTlo = (u16*)w;        w += 65536;

    prep_k<<<16384 + 128, 256, 0, stream>>>(A, W, mask_ws, smax_ws, WThi, WTlo);
    proj_k<<<CB * (CN / 16), 256, 0, stream>>>(X, WThi, WTlo, AK, hT, s_ws, e_ws, smax_ws);
    attn_k<<<CB * (CN / IT), 512, 0, stream>>>(hT, s_ws, e_ws, smax_ws, mask_ws, out);
}

// Round 6
// 83.567 us; speedup vs baseline: 1.3830x; 1.3830x over previous
//
#include <hip/hip_runtime.h>
#include <hip/hip_bf16.h>

typedef __attribute__((ext_vector_type(8))) short short8;
typedef __attribute__((ext_vector_type(4))) float f32x4;
typedef unsigned short u16;
typedef unsigned int u32;

constexpr int CB = 4, CN = 2048, CF = 128, CD = 64, CH = 4;
constexpr int IT = 32;   // i-rows per attn block

__device__ inline u32 fmap(float f) {
    u32 b = __float_as_uint(f);
    return b ^ ((u32)(((int)b) >> 31) | 0x80000000u);
}
__device__ inline float funmap(u32 u) {
    u32 b = (u & 0x80000000u) ? (u ^ 0x80000000u) : ~u;
    return __uint_as_float(b);
}
__device__ inline u16 bf16bits(float v) {
    __hip_bfloat16 b = __float2bfloat16(v);
    return *reinterpret_cast<u16*>(&b);
}

// ---------------------------------------------------------------------------
// Kernel 0: fused prep. Blocks [0,16384): pack adjacency -> bitmask (+ init
// smax). Blocks [16384,16512): W [H][F][D] f32 -> WT hi/lo bf16 [H][D][F].
// ---------------------------------------------------------------------------
__global__ __launch_bounds__(256) void prep_k(const int* __restrict__ A,
                                              const float* __restrict__ W,
                                              u32* __restrict__ mask,
                                              u32* __restrict__ smax_u,
                                              u16* __restrict__ WThi,
                                              u16* __restrict__ WTlo) {
    int blk = blockIdx.x, t = threadIdx.x;
    if (blk < 16384) {
        int gid = blk * 256 + t;
        if (blk == 0 && t < CH * CB) smax_u[t] = 0u;  // ~ -inf under fmap
        unsigned long long mk = __ballot(A[gid] > 0);
        if ((t & 63) == 0) {
            mask[gid >> 5] = (u32)mk;
            mask[(gid >> 5) + 1] = (u32)(mk >> 32);
        }
    } else {
        int idx = (blk - 16384) * 256 + t;   // H*F*D = 32768
        int h = idx >> 13;
        int f = (idx >> 6) & 127;
        int d = idx & 63;
        float v = W[idx];
        __hip_bfloat16 bh = __float2bfloat16(v);
        float lo = v - __bfloat162float(bh);
        int o = (h * CD + d) * CF + f;
        WThi[o] = *reinterpret_cast<u16*>(&bh);
        WTlo[o] = bf16bits(lo);
    }
}

// ---------------------------------------------------------------------------
// Kernel 1: MFMA projection. wave = (head, 16-row tile); block = 4 waves.
// Split-bf16: Xhi*Whi + Xhi*Wlo + Xlo*Whi.
// Emits hT bf16 [h][b][d][j], s f32, E=exp(s) f32, smax atomicMax.
// ---------------------------------------------------------------------------
__global__ __launch_bounds__(256) void proj_k(const float* __restrict__ X,
                                              const u16* __restrict__ WThi,
                                              const u16* __restrict__ WTlo,
                                              const float* __restrict__ AK,
                                              u16* __restrict__ hT,
                                              float* __restrict__ sout,
                                              float* __restrict__ eout,
                                              u32* __restrict__ smax_u) {
    __shared__ float tr[4][CD][17];   // per-wave transpose staging

    int blk = blockIdx.x;             // b*128 + ntile
    int ntile = blk & 127;
    int b = blk >> 7;
    int n0 = ntile * 16;
    int t = threadIdx.x;
    int w = t >> 6, l = t & 63;
    int h = w;
    int row_l = l & 15, jg = l >> 4;

    const float* xrow = X + ((size_t)b * CN + n0 + row_l) * CF + jg * 8;
    const u16* whi = WThi + (size_t)h * CD * CF;
    const u16* wlo = WTlo + (size_t)h * CD * CF;

    f32x4 c[4];
    f32x4 zero = {0.f, 0.f, 0.f, 0.f};
#pragma unroll
    for (int dt = 0; dt < 4; ++dt) c[dt] = zero;

#pragma unroll
    for (int kk = 0; kk < 4; ++kk) {
        float4 xa = *reinterpret_cast<const float4*>(xrow + kk * 32);
        float4 xb = *reinterpret_cast<const float4*>(xrow + kk * 32 + 4);
        float xv[8] = {xa.x, xa.y, xa.z, xa.w, xb.x, xb.y, xb.z, xb.w};
        short8 ahi, alo;
#pragma unroll
        for (int e = 0; e < 8; ++e) {
            __hip_bfloat16 bh = __float2bfloat16(xv[e]);
            ahi[e] = (short)*reinterpret_cast<u16*>(&bh);
            alo[e] = (short)bf16bits(xv[e] - __bfloat162float(bh));
        }
#pragma unroll
        for (int dt = 0; dt < 4; ++dt) {
            const u16* wp = whi + (dt * 16 + row_l) * CF + kk * 32 + jg * 8;
            const u16* wq = wlo + (dt * 16 + row_l) * CF + kk * 32 + jg * 8;
            short8 bhi = *reinterpret_cast<const short8*>(wp);
            short8 blo = *reinterpret_cast<const short8*>(wq);
            c[dt] = __builtin_amdgcn_mfma_f32_16x16x32_bf16(ahi, bhi, c[dt], 0, 0, 0);
            c[dt] = __builtin_amdgcn_mfma_f32_16x16x32_bf16(ahi, blo, c[dt], 0, 0, 0);
            c[dt] = __builtin_amdgcn_mfma_f32_16x16x32_bf16(alo, bhi, c[dt], 0, 0, 0);
        }
    }

    // ---- s = h . a ----
    float av[4];
#pragma unroll
    for (int dt = 0; dt < 4; ++dt) av[dt] = AK[h * CD + dt * 16 + row_l];
    float sacc[4];
#pragma unroll
    for (int r = 0; r < 4; ++r)
        sacc[r] = c[0][r] * av[0] + c[1][r] * av[1] + c[2][r] * av[2] + c[3][r] * av[3];
#pragma unroll
    for (int off = 1; off <= 8; off <<= 1)
#pragma unroll
        for (int r = 0; r < 4; ++r) sacc[r] += __shfl_xor(sacc[r], off, 64);

    float mx = fmaxf(fmaxf(sacc[0], sacc[1]), fmaxf(sacc[2], sacc[3]));
    mx = fmaxf(mx, __shfl_xor(mx, 16, 64));
    mx = fmaxf(mx, __shfl_xor(mx, 32, 64));
    if (l == 0) atomicMax(&smax_u[h * CB + b], fmap(mx));

    if (row_l == 0) {
#pragma unroll
        for (int r = 0; r < 4; ++r) {
            size_t si = (size_t)(h * CB + b) * CN + n0 + jg * 4 + r;
            sout[si] = sacc[r];
            eout[si] = __expf(sacc[r]);
        }
    }

    // ---- transpose h to d-major bf16 hT via LDS ----
#pragma unroll
    for (int dt = 0; dt < 4; ++dt)
#pragma unroll
        for (int r = 0; r < 4; ++r) tr[w][dt * 16 + row_l][jg * 4 + r] = c[dt][r];
    __syncthreads();

#pragma unroll
    for (int ch = 0; ch < 2; ++ch) {
        short8 pk;
#pragma unroll
        for (int e = 0; e < 8; ++e) pk[e] = (short)bf16bits(tr[w][l][ch * 8 + e]);
        *reinterpret_cast<short8*>(hT + ((size_t)((h * CB + b) * CD + l)) * CN + n0 + ch * 8) = pk;
    }
}

// ---------------------------------------------------------------------------
// Kernel 2: fused flash PV + head-mean + leaky.
// block = (b, 32-row i-tile), 1024 threads = 16 waves = (head hq, K-quarter
// jq of 512). Grid = 4*64 = 256 (1 block/CU, 4 waves/SIMD).
// Per wave: is=2 A-frags (weights in-register, no transcendentals),
// 4 B-frags/kk -> 10 MFMAs/kk. E_j staged in LDS. Denominator = ones-MFMA
// of the SAME bf16-rounded A-frag. Cross-wave reduce via LDS (2 slots,
// store round + add round), fused epilogue writes final out.
// ---------------------------------------------------------------------------
__global__ __launch_bounds__(1024, 4) void attn_k(const u16* __restrict__ hT,
                                                  const float* __restrict__ s_ws,
                                                  const float* __restrict__ e_ws,
                                                  const u32* __restrict__ smax_u,
                                                  const u32* __restrict__ mask32,
                                                  float* __restrict__ out) {
    __shared__ alignas(16) float e_sl[CH][CN];   // 32 KB
    __shared__ u32 m_lds[IT][65];                // 8.3 KB (pad)
    __shared__ float cbuf[CH][2][IT][68];        // 69.6 KB (pad 68 -> 2-way max)
    __shared__ float lbuf[CH][4][IT];            // 2 KB

    int blk = blockIdx.x;
    int b = blk >> 6;
    int i0 = (blk & 63) * IT;
    int t = threadIdx.x, w = t >> 6, l = t & 63;
    int hq = w >> 2, jq = w & 3;
    int row_l = l & 15, jg = l >> 4;
    int j_base = jq * 512;

    for (int idx = t; idx < CH * CN; idx += 1024) {
        int hh = idx >> 11, j = idx & 2047;
        e_sl[hh][j] = e_ws[(size_t)(hh * CB + b) * CN + j];
    }
    for (int idx = t; idx < IT * 64; idx += 1024) {
        int r = idx >> 6, wd = idx & 63;
        m_lds[r][wd] = mask32[(size_t)(i0 + r) * 64 + wd];
    }
    __syncthreads();

    float smax = funmap(smax_u[hq * CB + b]);
    float Ei[2], Ci[2];
#pragma unroll
    for (int is = 0; is < 2; ++is) {
        float si = s_ws[(size_t)(hq * CB + b) * CN + i0 + is * 16 + row_l];
        float m = fmaxf(si + smax, 0.f);
        Ei[is] = __expf(si - m);
        Ci[is] = __expf(-m);
    }

    f32x4 c[2][4], cl[2];
    f32x4 zero = {0.f, 0.f, 0.f, 0.f};
#pragma unroll
    for (int is = 0; is < 2; ++is) {
        cl[is] = zero;
#pragma unroll
        for (int dt = 0; dt < 4; ++dt) c[is][dt] = zero;
    }

    short8 ones;
#pragma unroll
    for (int e = 0; e < 8; ++e) ones[e] = (short)0x3F80;  // bf16 1.0

    const u16* bp[4];
#pragma unroll
    for (int dt = 0; dt < 4; ++dt)
        bp[dt] = hT + ((size_t)((hq * CB + b) * CD + dt * 16 + row_l)) * CN + j_base + jg * 8;

#pragma unroll 2
    for (int kk = 0; kk < 16; ++kk) {
        int j0 = kk * 32;
        short8 bf[4];
#pragma unroll
        for (int dt = 0; dt < 4; ++dt)
            bf[dt] = *reinterpret_cast<const short8*>(bp[dt] + j0);

        int jl = j_base + j0 + jg * 8;
        f32x4 ej0 = *reinterpret_cast<const f32x4*>(&e_sl[hq][jl]);
        f32x4 ej1 = *reinterpret_cast<const f32x4*>(&e_sl[hq][jl + 4]);

        short8 af[2];
#pragma unroll
        for (int is = 0; is < 2; ++is) {
            u32 byte = m_lds[is * 16 + row_l][jq * 16 + kk] >> (jg * 8);
#pragma unroll
            for (int e = 0; e < 8; ++e) {
                float ejv = (e < 4) ? ej0[e] : ej1[e - 4];
                float wv = ((byte >> e) & 1u) ? fmaxf(Ei[is] * ejv, Ci[is]) : 0.f;
                af[is][e] = (short)bf16bits(wv);
            }
        }

#pragma unroll
        for (int is = 0; is < 2; ++is) {
#pragma unroll
            for (int dt = 0; dt < 4; ++dt)
                c[is][dt] = __builtin_amdgcn_mfma_f32_16x16x32_bf16(af[is], bf[dt], c[is][dt], 0, 0, 0);
            cl[is] = __builtin_amdgcn_mfma_f32_16x16x32_bf16(af[is], ones, cl[is], 0, 0, 0);
        }
    }

    // ---- cross-wave reduction over K-quarters via 2 LDS slots ----
    // C/D layout: col = lane&15, row = (lane>>4)*4 + reg
    int slot = jq & 1;
    if (row_l == 0)
#pragma unroll
        for (int is = 0; is < 2; ++is)
#pragma unroll
            for (int r = 0; r < 4; ++r)
                lbuf[hq][jq][is * 16 + jg * 4 + r] = cl[is][r];
    if (jq < 2) {
#pragma unroll
        for (int is = 0; is < 2; ++is)
#pragma unroll
            for (int dt = 0; dt < 4; ++dt)
#pragma unroll
                for (int r = 0; r < 4; ++r)
                    cbuf[hq][slot][is * 16 + jg * 4 + r][dt * 16 + row_l] = c[is][dt][r];
    }
    __syncthreads();
    if (jq >= 2) {
#pragma unroll
        for (int is = 0; is < 2; ++is)
#pragma unroll
            for (int dt = 0; dt < 4; ++dt)
#pragma unroll
                for (int r = 0; r < 4; ++r)
                    cbuf[hq][slot][is * 16 + jg * 4 + r][dt * 16 + row_l] += c[is][dt][r];
    }
    __syncthreads();

    // ---- epilogue: quarter-sum, divide, head-mean, leaky, store ----
    for (int idx = t; idx < IT * CD; idx += 1024) {
        int row = idx >> 6, d = idx & 63;
        float acc = 0.f;
#pragma unroll
        for (int h = 0; h < CH; ++h) {
            float num = cbuf[h][0][row][d] + cbuf[h][1][row][d];
            float den = lbuf[h][0][row] + lbuf[h][1][row] + lbuf[h][2][row] + lbuf[h][3][row];
            acc += num / fmaxf(den, 1e-30f);
        }
        float o = acc * 0.25f;
        out[((size_t)b * CN + i0 + row) * CD + d] = o > 0.f ? o : 0.2f * o;
    }
}

// ---------------------------------------------------------------------------
extern "C" void kernel_launch(void* const* d_in, const int* in_sizes, int n_in,
                              void* d_out, int out_size, void* d_ws, size_t ws_size,
                              hipStream_t stream) {
    const float* X  = (const float*)d_in[0];   // [B,N,F]
    const int*   A  = (const int*)d_in[1];     // [N,N]
    const float* W  = (const float*)d_in[2];   // [H,F,D]
    const float* AK = (const float*)d_in[3];   // [H,D]
    float* out = (float*)d_out;                // [B,N,D]

    char* w = (char*)d_ws;
    float* s_ws = (float*)w;    w += 131072;     // 16*2048 f32
    float* e_ws = (float*)w;    w += 131072;     // 16*2048 f32
    u32* smax_ws = (u32*)w;     w += 256;
    u32* mask_ws = (u32*)w;     w += 524288;     // 2048*64 u32
    u16* hT = (u16*)w;          w += 4194304;    // 16*64*2048 bf16
    u16* WThi = (u16*)w;        w += 65536;      // 4*64*128 bf16
    u16* WTlo = (u16*)w;        w += 65536;

    prep_k<<<16384 + 128, 256, 0, stream>>>(A, W, mask_ws, smax_ws, WThi, WTlo);
    proj_k<<<CB * (CN / 16), 256, 0, stream>>>(X, WThi, WTlo, AK, hT, s_ws, e_ws, smax_ws);
    attn_k<<<CB * (CN / IT), 1024, 0, stream>>>(hT, s_ws, e_ws, smax_ws, mask_ws, out);
}

// Round 7
// 68.850 us; speedup vs baseline: 1.6786x; 1.2138x over previous
//
#include <hip/hip_runtime.h>
#include <hip/hip_bf16.h>

typedef __attribute__((ext_vector_type(8))) short short8;
typedef __attribute__((ext_vector_type(4))) float f32x4;
typedef unsigned short u16;
typedef unsigned int u32;

constexpr int CB = 4, CN = 2048, CF = 128, CD = 64, CH = 4;
constexpr int IT = 32;   // i-rows per attn block

__device__ inline u32 fmap(float f) {
    u32 b = __float_as_uint(f);
    return b ^ ((u32)(((int)b) >> 31) | 0x80000000u);
}
__device__ inline float funmap(u32 u) {
    u32 b = (u & 0x80000000u) ? (u ^ 0x80000000u) : ~u;
    return __uint_as_float(b);
}
__device__ inline u16 bf16bits(float v) {
    __hip_bfloat16 b = __float2bfloat16(v);
    return *reinterpret_cast<u16*>(&b);
}

// ---------------------------------------------------------------------------
// Kernel 0: fused prep. Blocks [0,16384): pack adjacency -> bitmask (+ init
// smax). Blocks [16384,16512): W [H][F][D] f32 -> WT hi/lo bf16 [H][D][F].
// ---------------------------------------------------------------------------
__global__ __launch_bounds__(256) void prep_k(const int* __restrict__ A,
                                              const float* __restrict__ W,
                                              u32* __restrict__ mask,
                                              u32* __restrict__ smax_u,
                                              u16* __restrict__ WThi,
                                              u16* __restrict__ WTlo) {
    int blk = blockIdx.x, t = threadIdx.x;
    if (blk < 16384) {
        int gid = blk * 256 + t;
        if (blk == 0 && t < CH * CB) smax_u[t] = 0u;  // ~ -inf under fmap
        unsigned long long mk = __ballot(A[gid] > 0);
        if ((t & 63) == 0) {
            mask[gid >> 5] = (u32)mk;
            mask[(gid >> 5) + 1] = (u32)(mk >> 32);
        }
    } else {
        int idx = (blk - 16384) * 256 + t;   // H*F*D = 32768
        int h = idx >> 13;
        int f = (idx >> 6) & 127;
        int d = idx & 63;
        float v = W[idx];
        __hip_bfloat16 bh = __float2bfloat16(v);
        float lo = v - __bfloat162float(bh);
        int o = (h * CD + d) * CF + f;
        WThi[o] = *reinterpret_cast<u16*>(&bh);
        WTlo[o] = bf16bits(lo);
    }
}

// ---------------------------------------------------------------------------
// Kernel 1: MFMA projection, fully load-hoisted. wave = head; block = 16-row
// tile. Split-bf16: Xhi*Whi + Xhi*Wlo + Xlo*Whi.
// hT layout: 16B unit = 8 consecutive j at fixed d: unit[(hb*256 + jc)*64 + d]
// -> coalesced stores here, 4x256B segments per B-load in attn.
// ---------------------------------------------------------------------------
__global__ __launch_bounds__(256, 2) void proj_k(const float* __restrict__ X,
                                                 const u16* __restrict__ WThi,
                                                 const u16* __restrict__ WTlo,
                                                 const float* __restrict__ AK,
                                                 u16* __restrict__ hT,
                                                 float* __restrict__ sout,
                                                 float* __restrict__ eout,
                                                 u32* __restrict__ smax_u) {
    __shared__ float tr[4][CD][17];   // per-wave transpose staging (17.4 KB)

    int blk = blockIdx.x;             // b*128 + ntile
    int ntile = blk & 127;
    int b = blk >> 7;
    int n0 = ntile * 16;
    int t = threadIdx.x;
    int w = t >> 6, l = t & 63;
    int h = w;
    int row_l = l & 15, jg = l >> 4;

    const float* xrow = X + ((size_t)b * CN + n0 + row_l) * CF + jg * 8;
    const u16* whi = WThi + (size_t)h * CD * CF;
    const u16* wlo = WTlo + (size_t)h * CD * CF;

    // ---- hoist ALL loads (8 X float4 + 32 WT short8) ----
    float4 xa[4], xb[4];
#pragma unroll
    for (int kk = 0; kk < 4; ++kk) {
        xa[kk] = *reinterpret_cast<const float4*>(xrow + kk * 32);
        xb[kk] = *reinterpret_cast<const float4*>(xrow + kk * 32 + 4);
    }
    short8 bhi[4][4], blo[4][4];
#pragma unroll
    for (int kk = 0; kk < 4; ++kk)
#pragma unroll
        for (int dt = 0; dt < 4; ++dt) {
            int off = (dt * 16 + row_l) * CF + kk * 32 + jg * 8;
            bhi[kk][dt] = *reinterpret_cast<const short8*>(whi + off);
            blo[kk][dt] = *reinterpret_cast<const short8*>(wlo + off);
        }

    f32x4 c[4];
    f32x4 zero = {0.f, 0.f, 0.f, 0.f};
#pragma unroll
    for (int dt = 0; dt < 4; ++dt) c[dt] = zero;

#pragma unroll
    for (int kk = 0; kk < 4; ++kk) {
        float xv[8] = {xa[kk].x, xa[kk].y, xa[kk].z, xa[kk].w,
                       xb[kk].x, xb[kk].y, xb[kk].z, xb[kk].w};
        short8 ahi, alo;
#pragma unroll
        for (int e = 0; e < 8; ++e) {
            __hip_bfloat16 bh = __float2bfloat16(xv[e]);
            ahi[e] = (short)*reinterpret_cast<u16*>(&bh);
            alo[e] = (short)bf16bits(xv[e] - __bfloat162float(bh));
        }
#pragma unroll
        for (int dt = 0; dt < 4; ++dt) {
            c[dt] = __builtin_amdgcn_mfma_f32_16x16x32_bf16(ahi, bhi[kk][dt], c[dt], 0, 0, 0);
            c[dt] = __builtin_amdgcn_mfma_f32_16x16x32_bf16(ahi, blo[kk][dt], c[dt], 0, 0, 0);
            c[dt] = __builtin_amdgcn_mfma_f32_16x16x32_bf16(alo, bhi[kk][dt], c[dt], 0, 0, 0);
        }
    }

    // ---- s = h . a ----
    float av[4];
#pragma unroll
    for (int dt = 0; dt < 4; ++dt) av[dt] = AK[h * CD + dt * 16 + row_l];
    float sacc[4];
#pragma unroll
    for (int r = 0; r < 4; ++r)
        sacc[r] = c[0][r] * av[0] + c[1][r] * av[1] + c[2][r] * av[2] + c[3][r] * av[3];
#pragma unroll
    for (int off = 1; off <= 8; off <<= 1)
#pragma unroll
        for (int r = 0; r < 4; ++r) sacc[r] += __shfl_xor(sacc[r], off, 64);

    float mx = fmaxf(fmaxf(sacc[0], sacc[1]), fmaxf(sacc[2], sacc[3]));
    mx = fmaxf(mx, __shfl_xor(mx, 16, 64));
    mx = fmaxf(mx, __shfl_xor(mx, 32, 64));
    if (l == 0) atomicMax(&smax_u[h * CB + b], fmap(mx));

    if (row_l == 0) {
#pragma unroll
        for (int r = 0; r < 4; ++r) {
            size_t si = (size_t)(h * CB + b) * CN + n0 + jg * 4 + r;
            sout[si] = sacc[r];
            eout[si] = __expf(sacc[r]);
        }
    }

    // ---- transpose to new hT layout via LDS; coalesced 16B stores ----
#pragma unroll
    for (int dt = 0; dt < 4; ++dt)
#pragma unroll
        for (int r = 0; r < 4; ++r) tr[w][dt * 16 + row_l][jg * 4 + r] = c[dt][r];
    __syncthreads();

    short8* hTs = reinterpret_cast<short8*>(hT);
    int jc = l >> 5, d0 = l & 31;
#pragma unroll
    for (int half = 0; half < 2; ++half) {
        short8 pk;
#pragma unroll
        for (int e = 0; e < 8; ++e)
            pk[e] = (short)bf16bits(tr[w][half * 32 + d0][jc * 8 + e]);
        hTs[((size_t)(h * CB + b) * 256 + ntile * 2 + jc) * 64 + half * 32 + d0] = pk;
    }
}

// ---------------------------------------------------------------------------
// Kernel 2: fused flash PV + head-mean + leaky. 1024 thr = 16 waves =
// (head hq, K-quarter jq of 512). Grid 256, XCD-swizzled so each XCD owns
// one b (hT slice L2-resident). Depth-1 prefetch of B-frags (bfA/bfB).
// Weight w = mask ? max(Ei*Ej, Ci) : 0; denominator = ones-MFMA of the SAME
// bf16-rounded A-frag. Cross-wave reduce via LDS; fused epilogue.
// ---------------------------------------------------------------------------
__global__ __launch_bounds__(1024, 4) void attn_k(const u16* __restrict__ hT,
                                                  const float* __restrict__ s_ws,
                                                  const float* __restrict__ e_ws,
                                                  const u32* __restrict__ smax_u,
                                                  const u32* __restrict__ mask32,
                                                  float* __restrict__ out) {
    __shared__ alignas(16) float e_sl[CH][CN];   // 32 KB
    __shared__ u32 m_lds[IT][65];                // 8.3 KB
    __shared__ float cbuf[CH][2][IT][68];        // 69.6 KB
    __shared__ float lbuf[CH][4][IT];            // 2 KB

    int orig = blockIdx.x;
    int xcd = orig & 7, pos = orig >> 3;   // round-robin XCD assignment
    int b = xcd >> 1;                      // each XCD serves exactly one b
    int it = (xcd & 1) * 32 + pos;         // tile 0..63
    int i0 = it * IT;
    int t = threadIdx.x, w = t >> 6, l = t & 63;
    int hq = w >> 2, jq = w & 3;
    int row_l = l & 15, jg = l >> 4;

    for (int idx = t; idx < CH * CN; idx += 1024) {
        int hh = idx >> 11, j = idx & 2047;
        e_sl[hh][j] = e_ws[(size_t)(hh * CB + b) * CN + j];
    }
    for (int idx = t; idx < IT * 64; idx += 1024) {
        int r = idx >> 6, wd = idx & 63;
        m_lds[r][wd] = mask32[(size_t)(i0 + r) * 64 + wd];
    }
    __syncthreads();

    float smax = funmap(smax_u[hq * CB + b]);
    float si0 = s_ws[(size_t)(hq * CB + b) * CN + i0 + row_l];
    float si1 = s_ws[(size_t)(hq * CB + b) * CN + i0 + 16 + row_l];
    float m0 = fmaxf(si0 + smax, 0.f), m1 = fmaxf(si1 + smax, 0.f);
    float Ei0 = __expf(si0 - m0), Ci0 = __expf(-m0);
    float Ei1 = __expf(si1 - m1), Ci1 = __expf(-m1);

    f32x4 c0[4], c1[4], cl0, cl1;
    f32x4 zero = {0.f, 0.f, 0.f, 0.f};
#pragma unroll
    for (int dt = 0; dt < 4; ++dt) { c0[dt] = zero; c1[dt] = zero; }
    cl0 = zero; cl1 = zero;

    short8 ones;
#pragma unroll
    for (int e = 0; e < 8; ++e) ones[e] = (short)0x3F80;  // bf16 1.0

    // B pointer: unit[(hb*256 + jq*64 + kk*4 + jg)*64 + dt*16 + row_l]
    const short8* hp = reinterpret_cast<const short8*>(hT) +
                       ((size_t)(hq * CB + b) * 256 + jq * 64 + jg) * 64 + row_l;

    short8 bfA[4], bfB[4];
#pragma unroll
    for (int dt = 0; dt < 4; ++dt) bfA[dt] = hp[dt * 16];

#define ATTN_STEP(KK, BCUR, BNXT, KNXT)                                          \
    do {                                                                         \
        _Pragma("unroll") for (int dt = 0; dt < 4; ++dt)                         \
            BNXT[dt] = hp[(KNXT) * 256 + dt * 16];                               \
        int jl = jq * 512 + (KK) * 32 + jg * 8;                                  \
        f32x4 ej0 = *reinterpret_cast<const f32x4*>(&e_sl[hq][jl]);              \
        f32x4 ej1 = *reinterpret_cast<const f32x4*>(&e_sl[hq][jl + 4]);          \
        u32 by0 = m_lds[row_l][jq * 16 + (KK)] >> (jg * 8);                      \
        u32 by1 = m_lds[16 + row_l][jq * 16 + (KK)] >> (jg * 8);                 \
        short8 af0, af1;                                                         \
        _Pragma("unroll") for (int e = 0; e < 8; ++e) {                          \
            float ejv = (e < 4) ? ej0[e] : ej1[e - 4];                           \
            float w0 = ((by0 >> e) & 1u) ? fmaxf(Ei0 * ejv, Ci0) : 0.f;          \
            float w1 = ((by1 >> e) & 1u) ? fmaxf(Ei1 * ejv, Ci1) : 0.f;          \
            af0[e] = (short)bf16bits(w0);                                        \
            af1[e] = (short)bf16bits(w1);                                        \
        }                                                                        \
        _Pragma("unroll") for (int dt = 0; dt < 4; ++dt) {                       \
            c0[dt] = __builtin_amdgcn_mfma_f32_16x16x32_bf16(af0, BCUR[dt], c0[dt], 0, 0, 0); \
            c1[dt] = __builtin_amdgcn_mfma_f32_16x16x32_bf16(af1, BCUR[dt], c1[dt], 0, 0, 0); \
        }                                                                        \
        cl0 = __builtin_amdgcn_mfma_f32_16x16x32_bf16(af0, ones, cl0, 0, 0, 0);  \
        cl1 = __builtin_amdgcn_mfma_f32_16x16x32_bf16(af1, ones, cl1, 0, 0, 0);  \
    } while (0)

#pragma unroll
    for (int kp = 0; kp < 8; ++kp) {
        ATTN_STEP(2 * kp, bfA, bfB, 2 * kp + 1);
        ATTN_STEP(2 * kp + 1, bfB, bfA, (2 * kp + 2 < 16) ? 2 * kp + 2 : 15);
    }
#undef ATTN_STEP

    // ---- cross-wave reduction over K-quarters via 2 LDS slots ----
    // C/D layout: col = lane&15, row = (lane>>4)*4 + reg
    int slot = jq & 1;
    if (row_l == 0)
#pragma unroll
        for (int r = 0; r < 4; ++r) {
            lbuf[hq][jq][jg * 4 + r] = cl0[r];
            lbuf[hq][jq][16 + jg * 4 + r] = cl1[r];
        }
    if (jq < 2) {
#pragma unroll
        for (int dt = 0; dt < 4; ++dt)
#pragma unroll
            for (int r = 0; r < 4; ++r) {
                cbuf[hq][slot][jg * 4 + r][dt * 16 + row_l] = c0[dt][r];
                cbuf[hq][slot][16 + jg * 4 + r][dt * 16 + row_l] = c1[dt][r];
            }
    }
    __syncthreads();
    if (jq >= 2) {
#pragma unroll
        for (int dt = 0; dt < 4; ++dt)
#pragma unroll
            for (int r = 0; r < 4; ++r) {
                cbuf[hq][slot][jg * 4 + r][dt * 16 + row_l] += c0[dt][r];
                cbuf[hq][slot][16 + jg * 4 + r][dt * 16 + row_l] += c1[dt][r];
            }
    }
    __syncthreads();

    // ---- epilogue: slot-sum, divide, head-mean, leaky, store ----
    for (int idx = t; idx < IT * CD; idx += 1024) {
        int row = idx >> 6, d = idx & 63;
        float acc = 0.f;
#pragma unroll
        for (int h = 0; h < CH; ++h) {
            float num = cbuf[h][0][row][d] + cbuf[h][1][row][d];
            float den = lbuf[h][0][row] + lbuf[h][1][row] + lbuf[h][2][row] + lbuf[h][3][row];
            acc += num / fmaxf(den, 1e-30f);
        }
        float o = acc * 0.25f;
        out[((size_t)b * CN + i0 + row) * CD + d] = o > 0.f ? o : 0.2f * o;
    }
}

// ---------------------------------------------------------------------------
extern "C" void kernel_launch(void* const* d_in, const int* in_sizes, int n_in,
                              void* d_out, int out_size, void* d_ws, size_t ws_size,
                              hipStream_t stream) {
    const float* X  = (const float*)d_in[0];   // [B,N,F]
    const int*   A  = (const int*)d_in[1];     // [N,N]
    const float* W  = (const float*)d_in[2];   // [H,F,D]
    const float* AK = (const float*)d_in[3];   // [H,D]
    float* out = (float*)d_out;                // [B,N,D]

    char* w = (char*)d_ws;
    float* s_ws = (float*)w;    w += 131072;     // 16*2048 f32
    float* e_ws = (float*)w;    w += 131072;     // 16*2048 f32
    u32* smax_ws = (u32*)w;     w += 256;
    u32* mask_ws = (u32*)w;     w += 524288;     // 2048*64 u32
    u16* hT = (u16*)w;          w += 4194304;    // 16*256*64 short8 units
    u16* WThi = (u16*)w;        w += 65536;      // 4*64*128 bf16
    u16* WTlo = (u16*)w;        w += 65536;

    prep_k<<<16384 + 128, 256, 0, stream>>>(A, W, mask_ws, smax_ws, WThi, WTlo);
    proj_k<<<CB * (CN / 16), 256, 0, stream>>>(X, WThi, WTlo, AK, hT, s_ws, e_ws, smax_ws);
    attn_k<<<CB * (CN / IT), 1024, 0, stream>>>(hT, s_ws, e_ws, smax_ws, mask_ws, out);
}